// Round 3
// baseline (263.703 us; speedup 1.0000x reference)
//
#include <hip/hip_runtime.h>

typedef unsigned short u16;
typedef __bf16 bf16x8 __attribute__((ext_vector_type(8)));
typedef float f32x4 __attribute__((ext_vector_type(4)));

__device__ __forceinline__ u16 f2bf(float f) {
  unsigned int u = __builtin_bit_cast(unsigned int, f);
  u += 0x7fffu + ((u >> 16) & 1u);
  return (u16)(u >> 16);
}
__device__ __forceinline__ float bf2f(u16 h) {
  unsigned int u = ((unsigned int)h) << 16;
  return __builtin_bit_cast(float, u);
}

// ---------------------------------------------------------------------------
// k_prep: fp32 weights -> bf16 MFMA B-fragment order.
// Fragment (ks, nt, lane): 8 elems W[ks*32 + (lane>>4)*8 + j][nt*16 + (lane&15)]
// at dst[((ks*16+nt)*64 + lane)*8 + j].
// ---------------------------------------------------------------------------
__global__ __launch_bounds__(256) void k_prep(
    const float* __restrict__ W1, const float* __restrict__ W2,
    const float* __restrict__ R1, const float* __restrict__ R2, const float* __restrict__ R3,
    u16* __restrict__ W1s, u16* __restrict__ W2s,
    u16* __restrict__ R1s, u16* __restrict__ R2s, u16* __restrict__ R3s) {
  int t = blockIdx.x * 256 + threadIdx.x;
  const float* src; u16* dst; int lt;
  if (t < 12288) { src = W1; dst = W1s; lt = t; }
  else {
    int u = t - 12288;
    int m = u >> 13;
    lt = u & 8191;
    if (m == 0)      { src = W2; dst = W2s; }
    else if (m == 1) { src = R1; dst = R1s; }
    else if (m == 2) { src = R2; dst = R2s; }
    else if (m == 3) { src = R3; dst = R3s; }
    else return;
  }
  int lane = lt & 63;
  int nt = (lt >> 6) & 15;
  int ks = lt >> 10;
  int col = nt * 16 + (lane & 15);
  int kb = ks * 32 + (lane >> 4) * 8;
  union { u16 u[8]; uint4 v; } o;
#pragma unroll
  for (int j = 0; j < 8; ++j) o.u[j] = f2bf(src[(size_t)(kb + j) * 256 + col]);
  *(uint4*)(dst + (size_t)lt * 8) = o.v;
}

// ---------------------------------------------------------------------------
// CSR build: histogram -> 3-stage multi-block exclusive scan -> scatter.
// ---------------------------------------------------------------------------
__global__ __launch_bounds__(256) void k_hist(const int* __restrict__ cells,
                                              int* __restrict__ counts, int E) {
  int e = blockIdx.x * 256 + threadIdx.x;
  if (e < E) atomicAdd(&counts[cells[e]], 1);
}

__global__ __launch_bounds__(256) void k_scan1(const int* __restrict__ counts,
                                               int* __restrict__ offs,
                                               int* __restrict__ bsum, int M) {
  __shared__ int ws[4];
  int tid = threadIdx.x, lane = tid & 63, wid = tid >> 6;
  int i = blockIdx.x * 256 + tid;
  int v = (i < M) ? counts[i] : 0;
  int x = v;
#pragma unroll
  for (int s = 1; s < 64; s <<= 1) { int y = __shfl_up(x, s); if (lane >= s) x += y; }
  if (lane == 63) ws[wid] = x;
  __syncthreads();
  int pre = 0;
#pragma unroll
  for (int w = 0; w < 4; ++w) if (w < wid) pre += ws[w];
  if (i < M) offs[i] = pre + x - v;
  if (tid == 255) bsum[blockIdx.x] = pre + x;
}

__global__ __launch_bounds__(256) void k_scan2(int* __restrict__ bsum, int nb) {
  __shared__ int ws[4];
  int tid = threadIdx.x, lane = tid & 63, wid = tid >> 6;
  int v = (tid < nb) ? bsum[tid] : 0;
  int x = v;
#pragma unroll
  for (int s = 1; s < 64; s <<= 1) { int y = __shfl_up(x, s); if (lane >= s) x += y; }
  if (lane == 63) ws[wid] = x;
  __syncthreads();
  int pre = 0;
#pragma unroll
  for (int w = 0; w < 4; ++w) if (w < wid) pre += ws[w];
  if (tid < nb) bsum[tid] = pre + x - v;
}

__global__ __launch_bounds__(256) void k_scan3(int* __restrict__ offs,
                                               const int* __restrict__ bsum,
                                               int* __restrict__ cursor, int M, int E) {
  int i = blockIdx.x * 256 + threadIdx.x;
  if (i < M) { int o = offs[i] + bsum[blockIdx.x]; offs[i] = o; cursor[i] = o; }
  if (i == M) offs[M] = E;
}

__global__ __launch_bounds__(256) void k_scatter(const int* __restrict__ cells,
                                                 const int* __restrict__ nodes,
                                                 int* __restrict__ cursor,
                                                 int* __restrict__ sorted, int E) {
  int e = blockIdx.x * 256 + threadIdx.x;
  if (e < E) {
    int c = cells[e];
    int p = atomicAdd(&cursor[c], 1);
    sorted[p] = nodes[e];
  }
}

// ---------------------------------------------------------------------------
// k_phi: H = relu(relu(X@W1+b1)@W2+b2), col-split, SINGLE 32KB LDS buffer,
// 4 blocks/CU, explicit next-ks weight prefetch chains.
// ---------------------------------------------------------------------------
__global__ __launch_bounds__(256, 4) void k_phi(
    const float* __restrict__ X,
    const u16* __restrict__ W1s, const float* __restrict__ b1,
    const u16* __restrict__ W2s, const float* __restrict__ b2,
    u16* __restrict__ H, int N) {
  __shared__ __align__(16) u16 buf[64 * 256];
  const int tid = threadIdx.x, lane = tid & 63, wid = tid >> 6;
  const int g = lane >> 4, r16 = lane & 15;
  const int rbase = blockIdx.x * 64;

  const u16* w1p = W1s + (size_t)(wid * 4) * 512 + lane * 8;  // + ks*8192 + n*512
  const u16* w2p = W2s + (size_t)(wid * 4) * 512 + lane * 8;

  f32x4 acc[4][4];
#pragma unroll
  for (int m = 0; m < 4; ++m)
#pragma unroll
    for (int n = 0; n < 4; ++n) acc[m][n] = (f32x4){0.f, 0.f, 0.f, 0.f};

  // kick off ks=0 weight loads so their latency overlaps the X staging
  bf16x8 bfr[4];
#pragma unroll
  for (int n = 0; n < 4; ++n) bfr[n] = *(const bf16x8*)(w1p + n * 512);

  // ---- stage phase 0: X cols [0,256) ----
#pragma unroll
  for (int it = 0; it < 16; ++it) {
    int u = it * 256 + tid;
    int row = u >> 6, c4 = u & 63;
    int crow = rbase + row; crow = crow < N ? crow : N - 1;
    f32x4 v = *(const f32x4*)(X + (size_t)crow * 384 + c4 * 4);
    uint2 pk;
    pk.x = (unsigned int)f2bf(v[0]) | ((unsigned int)f2bf(v[1]) << 16);
    pk.y = (unsigned int)f2bf(v[2]) | ((unsigned int)f2bf(v[3]) << 16);
    *(uint2*)(buf + row * 256 + ((c4 * 4) ^ ((row & 15) << 3))) = pk;
  }
  __syncthreads();

  // ---- layer 1, K phase 0 (ks 0..7) ----
#pragma unroll
  for (int ksl = 0; ksl < 8; ++ksl) {
    bf16x8 bnx[4];
#pragma unroll
    for (int n = 0; n < 4; ++n)
      bnx[n] = *(const bf16x8*)(w1p + (size_t)(ksl + 1) * 8192 + n * 512);  // ks 1..8
#pragma unroll
    for (int m = 0; m < 4; ++m) {
      int row = m * 16 + r16;
      bf16x8 af = *(const bf16x8*)(buf + row * 256 + ((ksl * 32 + g * 8) ^ (r16 << 3)));
#pragma unroll
      for (int n = 0; n < 4; ++n)
        acc[m][n] = __builtin_amdgcn_mfma_f32_16x16x32_bf16(af, bfr[n], acc[m][n], 0, 0, 0);
    }
#pragma unroll
    for (int n = 0; n < 4; ++n) bfr[n] = bnx[n];
  }
  __syncthreads();  // done reading phase-0 A

  // ---- stage phase 1: X cols [256,384) into buf u16-cols [0,128) ----
#pragma unroll
  for (int it = 0; it < 8; ++it) {
    int u = it * 256 + tid;
    int row = u >> 5, c4 = u & 31;
    int crow = rbase + row; crow = crow < N ? crow : N - 1;
    f32x4 v = *(const f32x4*)(X + (size_t)crow * 384 + 256 + c4 * 4);
    uint2 pk;
    pk.x = (unsigned int)f2bf(v[0]) | ((unsigned int)f2bf(v[1]) << 16);
    pk.y = (unsigned int)f2bf(v[2]) | ((unsigned int)f2bf(v[3]) << 16);
    *(uint2*)(buf + row * 256 + ((c4 * 4) ^ ((row & 15) << 3))) = pk;
  }
  __syncthreads();

  // ---- layer 1, K phase 1 (ks 8..11; bfr holds ks=8) ----
#pragma unroll
  for (int ksl = 0; ksl < 4; ++ksl) {
    bf16x8 bnx[4];
    if (ksl < 3) {
#pragma unroll
      for (int n = 0; n < 4; ++n)
        bnx[n] = *(const bf16x8*)(w1p + (size_t)(9 + ksl) * 8192 + n * 512);
    } else {
#pragma unroll
      for (int n = 0; n < 4; ++n)
        bnx[n] = *(const bf16x8*)(w2p + n * 512);  // prefetch layer-2 ks=0
    }
#pragma unroll
    for (int m = 0; m < 4; ++m) {
      int row = m * 16 + r16;
      bf16x8 af = *(const bf16x8*)(buf + row * 256 + ((ksl * 32 + g * 8) ^ (r16 << 3)));
#pragma unroll
      for (int n = 0; n < 4; ++n)
        acc[m][n] = __builtin_amdgcn_mfma_f32_16x16x32_bf16(af, bfr[n], acc[m][n], 0, 0, 0);
    }
#pragma unroll
    for (int n = 0; n < 4; ++n) bfr[n] = bnx[n];
  }
  __syncthreads();  // done reading phase-1 A; buf free for h1

  // ---- h1 = relu(acc + b1) -> buf ----
  float bias1[4];
#pragma unroll
  for (int n = 0; n < 4; ++n) bias1[n] = b1[wid * 64 + n * 16 + r16];
#pragma unroll
  for (int m = 0; m < 4; ++m)
#pragma unroll
    for (int n = 0; n < 4; ++n)
#pragma unroll
      for (int rr = 0; rr < 4; ++rr) {
        int row = m * 16 + g * 4 + rr;
        int col = wid * 64 + n * 16 + r16;
        float v = fmaxf(acc[m][n][rr] + bias1[n], 0.f);
        buf[row * 256 + (col ^ ((row & 15) << 3))] = f2bf(v);
      }
  __syncthreads();

  // ---- layer 2 (bfr holds W2 ks=0) ----
  f32x4 acc2[4][4];
#pragma unroll
  for (int m = 0; m < 4; ++m)
#pragma unroll
    for (int n = 0; n < 4; ++n) acc2[m][n] = (f32x4){0.f, 0.f, 0.f, 0.f};
#pragma unroll
  for (int ks = 0; ks < 8; ++ks) {
    bf16x8 bnx[4];
    if (ks < 7) {
#pragma unroll
      for (int n = 0; n < 4; ++n)
        bnx[n] = *(const bf16x8*)(w2p + (size_t)(ks + 1) * 8192 + n * 512);
    }
#pragma unroll
    for (int m = 0; m < 4; ++m) {
      int row = m * 16 + r16;
      bf16x8 af = *(const bf16x8*)(buf + row * 256 + ((ks * 32 + g * 8) ^ (r16 << 3)));
#pragma unroll
      for (int n = 0; n < 4; ++n)
        acc2[m][n] = __builtin_amdgcn_mfma_f32_16x16x32_bf16(af, bfr[n], acc2[m][n], 0, 0, 0);
    }
    if (ks < 7) {
#pragma unroll
      for (int n = 0; n < 4; ++n) bfr[n] = bnx[n];
    }
  }
  __syncthreads();  // done reading h1

  // ---- h2 = relu(acc2 + b2) -> buf ----
  float bias2[4];
#pragma unroll
  for (int n = 0; n < 4; ++n) bias2[n] = b2[wid * 64 + n * 16 + r16];
#pragma unroll
  for (int m = 0; m < 4; ++m)
#pragma unroll
    for (int n = 0; n < 4; ++n)
#pragma unroll
      for (int rr = 0; rr < 4; ++rr) {
        int row = m * 16 + g * 4 + rr;
        int col = wid * 64 + n * 16 + r16;
        float v = fmaxf(acc2[m][n][rr] + bias2[n], 0.f);
        buf[row * 256 + (col ^ ((row & 15) << 3))] = f2bf(v);
      }
  __syncthreads();

  // ---- coalesced copy out ----
#pragma unroll
  for (int it = 0; it < 8; ++it) {
    int u = it * 256 + tid;
    int row = u >> 5, k8 = u & 31;
    uint4 d = *(const uint4*)(buf + row * 256 + ((k8 * 8) ^ ((row & 15) << 3)));
    int grow = rbase + row;
    if (grow < N) *(uint4*)(H + (size_t)grow * 256 + k8 * 8) = d;
  }
}

// ---------------------------------------------------------------------------
// k_cellsum: one wave per cell; pre-resolve sorted indices, __shfl-broadcast,
// 4-wide unrolled H-row loads so loads issue back-to-back.
// ---------------------------------------------------------------------------
__global__ __launch_bounds__(256) void k_cellsum(
    const u16* __restrict__ H, const int* __restrict__ sorted,
    const int* __restrict__ offs, u16* __restrict__ CS, int M) {
  const int lane = threadIdx.x & 63, wid = threadIdx.x >> 6;
  int c = blockIdx.x * 4 + wid;
  if (c >= M) return;
  int s = offs[c], e = offs[c + 1];
  float a0 = 0.f, a1 = 0.f, a2 = 0.f, a3 = 0.f;
  for (int base = s; base < e; base += 64) {
    int cnt = e - base; if (cnt > 64) cnt = 64;
    int idx = sorted[base + (lane < cnt ? lane : 0)];
    int j = 0;
    for (; j + 4 <= cnt; j += 4) {
      int n0 = __shfl(idx, j), n1 = __shfl(idx, j + 1);
      int n2 = __shfl(idx, j + 2), n3 = __shfl(idx, j + 3);
      ushort4 h0 = *(const ushort4*)(H + (size_t)n0 * 256 + lane * 4);
      ushort4 h1 = *(const ushort4*)(H + (size_t)n1 * 256 + lane * 4);
      ushort4 h2 = *(const ushort4*)(H + (size_t)n2 * 256 + lane * 4);
      ushort4 h3 = *(const ushort4*)(H + (size_t)n3 * 256 + lane * 4);
      a0 += bf2f(h0.x) + bf2f(h1.x) + bf2f(h2.x) + bf2f(h3.x);
      a1 += bf2f(h0.y) + bf2f(h1.y) + bf2f(h2.y) + bf2f(h3.y);
      a2 += bf2f(h0.z) + bf2f(h1.z) + bf2f(h2.z) + bf2f(h3.z);
      a3 += bf2f(h0.w) + bf2f(h1.w) + bf2f(h2.w) + bf2f(h3.w);
    }
    for (; j < cnt; ++j) {
      int nd = __shfl(idx, j);
      ushort4 h = *(const ushort4*)(H + (size_t)nd * 256 + lane * 4);
      a0 += bf2f(h.x); a1 += bf2f(h.y); a2 += bf2f(h.z); a3 += bf2f(h.w);
    }
  }
  ushort4 o;
  o.x = f2bf(a0); o.y = f2bf(a1); o.z = f2bf(a2); o.w = f2bf(a3);
  *(ushort4*)(CS + (size_t)c * 256 + lane * 4) = o;
}

// ---------------------------------------------------------------------------
// k_rho: OUT = relu(relu(CS@R1+c1)@R2+c2)@R3+c3, single 32KB LDS buffer,
// 4 blocks/CU, prefetch chains across all 3 layers.
// ---------------------------------------------------------------------------
__global__ __launch_bounds__(256, 4) void k_rho(
    const u16* __restrict__ CS,
    const u16* __restrict__ R1s, const float* __restrict__ c1,
    const u16* __restrict__ R2s, const float* __restrict__ c2,
    const u16* __restrict__ R3s, const float* __restrict__ c3,
    float* __restrict__ OUT, int M) {
  __shared__ __align__(16) u16 buf[64 * 256];
  const int tid = threadIdx.x, lane = tid & 63, wid = tid >> 6;
  const int g = lane >> 4, r16 = lane & 15;
  const int rbase = blockIdx.x * 64;

  const u16* w1p = R1s + (size_t)(wid * 4) * 512 + lane * 8;
  const u16* w2p = R2s + (size_t)(wid * 4) * 512 + lane * 8;
  const u16* w3p = R3s + (size_t)(wid * 4) * 512 + lane * 8;

  bf16x8 bfr[4];
#pragma unroll
  for (int n = 0; n < 4; ++n) bfr[n] = *(const bf16x8*)(w1p + n * 512);

  // stage CS tile (already bf16)
#pragma unroll
  for (int it = 0; it < 8; ++it) {
    int u = it * 256 + tid;
    int row = u >> 5, k8 = u & 31;
    int crow = rbase + row; crow = crow < M ? crow : M - 1;
    uint4 d = *(const uint4*)(CS + (size_t)crow * 256 + k8 * 8);
    *(uint4*)(buf + row * 256 + ((k8 * 8) ^ ((row & 15) << 3))) = d;
  }
  __syncthreads();

  // ---- layer 1 ----
  f32x4 acc[4][4];
#pragma unroll
  for (int m = 0; m < 4; ++m)
#pragma unroll
    for (int n = 0; n < 4; ++n) acc[m][n] = (f32x4){0.f, 0.f, 0.f, 0.f};
#pragma unroll
  for (int ks = 0; ks < 8; ++ks) {
    bf16x8 bnx[4];
    if (ks < 7) {
#pragma unroll
      for (int n = 0; n < 4; ++n)
        bnx[n] = *(const bf16x8*)(w1p + (size_t)(ks + 1) * 8192 + n * 512);
    } else {
#pragma unroll
      for (int n = 0; n < 4; ++n)
        bnx[n] = *(const bf16x8*)(w2p + n * 512);  // prefetch R2 ks=0
    }
#pragma unroll
    for (int m = 0; m < 4; ++m) {
      int row = m * 16 + r16;
      bf16x8 af = *(const bf16x8*)(buf + row * 256 + ((ks * 32 + g * 8) ^ (r16 << 3)));
#pragma unroll
      for (int n = 0; n < 4; ++n)
        acc[m][n] = __builtin_amdgcn_mfma_f32_16x16x32_bf16(af, bfr[n], acc[m][n], 0, 0, 0);
    }
#pragma unroll
    for (int n = 0; n < 4; ++n) bfr[n] = bnx[n];
  }
  __syncthreads();  // done reading CS tile

  float bias1[4];
#pragma unroll
  for (int n = 0; n < 4; ++n) bias1[n] = c1[wid * 64 + n * 16 + r16];
#pragma unroll
  for (int m = 0; m < 4; ++m)
#pragma unroll
    for (int n = 0; n < 4; ++n)
#pragma unroll
      for (int rr = 0; rr < 4; ++rr) {
        int row = m * 16 + g * 4 + rr;
        int col = wid * 64 + n * 16 + r16;
        float v = fmaxf(acc[m][n][rr] + bias1[n], 0.f);
        buf[row * 256 + (col ^ ((row & 15) << 3))] = f2bf(v);
      }
  __syncthreads();

  // ---- layer 2 (bfr holds R2 ks=0) ----
  f32x4 acc2[4][4];
#pragma unroll
  for (int m = 0; m < 4; ++m)
#pragma unroll
    for (int n = 0; n < 4; ++n) acc2[m][n] = (f32x4){0.f, 0.f, 0.f, 0.f};
#pragma unroll
  for (int ks = 0; ks < 8; ++ks) {
    bf16x8 bnx[4];
    if (ks < 7) {
#pragma unroll
      for (int n = 0; n < 4; ++n)
        bnx[n] = *(const bf16x8*)(w2p + (size_t)(ks + 1) * 8192 + n * 512);
    } else {
#pragma unroll
      for (int n = 0; n < 4; ++n)
        bnx[n] = *(const bf16x8*)(w3p + n * 512);  // prefetch R3 ks=0
    }
#pragma unroll
    for (int m = 0; m < 4; ++m) {
      int row = m * 16 + r16;
      bf16x8 af = *(const bf16x8*)(buf + row * 256 + ((ks * 32 + g * 8) ^ (r16 << 3)));
#pragma unroll
      for (int n = 0; n < 4; ++n)
        acc2[m][n] = __builtin_amdgcn_mfma_f32_16x16x32_bf16(af, bfr[n], acc2[m][n], 0, 0, 0);
    }
#pragma unroll
    for (int n = 0; n < 4; ++n) bfr[n] = bnx[n];
  }
  __syncthreads();  // done reading h1

  float bias2[4];
#pragma unroll
  for (int n = 0; n < 4; ++n) bias2[n] = c2[wid * 64 + n * 16 + r16];
#pragma unroll
  for (int m = 0; m < 4; ++m)
#pragma unroll
    for (int n = 0; n < 4; ++n)
#pragma unroll
      for (int rr = 0; rr < 4; ++rr) {
        int row = m * 16 + g * 4 + rr;
        int col = wid * 64 + n * 16 + r16;
        float v = fmaxf(acc2[m][n][rr] + bias2[n], 0.f);
        buf[row * 256 + (col ^ ((row & 15) << 3))] = f2bf(v);
      }
  __syncthreads();

  // ---- layer 3 (no relu; bfr holds R3 ks=0), direct fp32 stores ----
  f32x4 acc3[4][4];
#pragma unroll
  for (int m = 0; m < 4; ++m)
#pragma unroll
    for (int n = 0; n < 4; ++n) acc3[m][n] = (f32x4){0.f, 0.f, 0.f, 0.f};
#pragma unroll
  for (int ks = 0; ks < 8; ++ks) {
    bf16x8 bnx[4];
    if (ks < 7) {
#pragma unroll
      for (int n = 0; n < 4; ++n)
        bnx[n] = *(const bf16x8*)(w3p + (size_t)(ks + 1) * 8192 + n * 512);
    }
#pragma unroll
    for (int m = 0; m < 4; ++m) {
      int row = m * 16 + r16;
      bf16x8 af = *(const bf16x8*)(buf + row * 256 + ((ks * 32 + g * 8) ^ (r16 << 3)));
#pragma unroll
      for (int n = 0; n < 4; ++n)
        acc3[m][n] = __builtin_amdgcn_mfma_f32_16x16x32_bf16(af, bfr[n], acc3[m][n], 0, 0, 0);
    }
    if (ks < 7) {
#pragma unroll
      for (int n = 0; n < 4; ++n) bfr[n] = bnx[n];
    }
  }
#pragma unroll
  for (int n = 0; n < 4; ++n) {
    float bias = c3[wid * 64 + n * 16 + r16];
#pragma unroll
    for (int m = 0; m < 4; ++m)
#pragma unroll
      for (int rr = 0; rr < 4; ++rr) {
        int grow = rbase + m * 16 + g * 4 + rr;
        if (grow < M) OUT[(size_t)grow * 256 + wid * 64 + n * 16 + r16] = acc3[m][n][rr] + bias;
      }
  }
}

// ---------------------------------------------------------------------------
extern "C" void kernel_launch(void* const* d_in, const int* in_sizes, int n_in,
                              void* d_out, int out_size, void* d_ws, size_t ws_size,
                              hipStream_t stream) {
  const float* X    = (const float*)d_in[0];
  const int* nodes  = (const int*)d_in[1];
  const int* cells  = (const int*)d_in[2];
  const float* W1   = (const float*)d_in[4];
  const float* b1   = (const float*)d_in[5];
  const float* W2   = (const float*)d_in[6];
  const float* b2   = (const float*)d_in[7];
  const float* R1   = (const float*)d_in[8];
  const float* c1   = (const float*)d_in[9];
  const float* R2   = (const float*)d_in[10];
  const float* c2   = (const float*)d_in[11];
  const float* R3   = (const float*)d_in[12];
  const float* c3   = (const float*)d_in[13];
  float* OUT = (float*)d_out;

  const int N = in_sizes[0] / 384;   // 100000
  const int E = in_sizes[1];         // 400000
  const int M = out_size / 256;      // 50000

  char* ws = (char*)d_ws;
  size_t off = 0;
  auto alloc = [&](size_t b) { size_t o = off; off += (b + 255) & ~(size_t)255; return o; };
  u16* W1s    = (u16*)(ws + alloc((size_t)12 * 16 * 64 * 8 * 2));
  u16* W2s    = (u16*)(ws + alloc((size_t)8 * 16 * 64 * 8 * 2));
  u16* R1s    = (u16*)(ws + alloc((size_t)8 * 16 * 64 * 8 * 2));
  u16* R2s    = (u16*)(ws + alloc((size_t)8 * 16 * 64 * 8 * 2));
  u16* R3s    = (u16*)(ws + alloc((size_t)8 * 16 * 64 * 8 * 2));
  u16* H      = (u16*)(ws + alloc((size_t)N * 256 * 2));
  u16* CS     = (u16*)(ws + alloc((size_t)M * 256 * 2));
  int* counts = (int*)(ws + alloc((size_t)M * 4));
  int* offs   = (int*)(ws + alloc((size_t)(M + 1) * 4));
  int* cursor = (int*)(ws + alloc((size_t)M * 4));
  int* sorted = (int*)(ws + alloc((size_t)E * 4));
  int* bsum   = (int*)(ws + alloc((size_t)256 * 4));

  const int NB = (M + 255) / 256;

  hipMemsetAsync(counts, 0, (size_t)M * 4, stream);
  k_prep<<<176, 256, 0, stream>>>(W1, W2, R1, R2, R3, W1s, W2s, R1s, R2s, R3s);
  k_hist<<<(E + 255) / 256, 256, 0, stream>>>(cells, counts, E);
  k_scan1<<<NB, 256, 0, stream>>>(counts, offs, bsum, M);
  k_scan2<<<1, 256, 0, stream>>>(bsum, NB);
  k_scan3<<<(M + 256) / 256, 256, 0, stream>>>(offs, bsum, cursor, M, E);
  k_scatter<<<(E + 255) / 256, 256, 0, stream>>>(cells, nodes, cursor, sorted, E);
  k_phi<<<(N + 63) / 64, 256, 0, stream>>>(X, W1s, b1, W2s, b2, H, N);
  k_cellsum<<<(M + 3) / 4, 256, 0, stream>>>(H, sorted, offs, CS, M);
  k_rho<<<(M + 63) / 64, 256, 0, stream>>>(CS, R1s, c1, R2s, c2, R3s, c3, OUT, M);
}

// Round 4
// 216.391 us; speedup vs baseline: 1.2186x; 1.2186x over previous
//
#include <hip/hip_runtime.h>

typedef unsigned short u16;
typedef __bf16 bf16x8 __attribute__((ext_vector_type(8)));
typedef float f32x4 __attribute__((ext_vector_type(4)));

__device__ __forceinline__ u16 f2bf(float f) {
  unsigned int u = __builtin_bit_cast(unsigned int, f);
  u += 0x7fffu + ((u >> 16) & 1u);
  return (u16)(u >> 16);
}
__device__ __forceinline__ float bf2f(u16 h) {
  unsigned int u = ((unsigned int)h) << 16;
  return __builtin_bit_cast(float, u);
}

// ---------------------------------------------------------------------------
// k_prep: fp32 weights -> bf16 MFMA B-fragment order.
// Fragment (ks, nt, lane): 8 elems W[ks*32 + (lane>>4)*8 + j][nt*16 + (lane&15)]
// at dst[((ks*16+nt)*64 + lane)*8 + j].
// ---------------------------------------------------------------------------
__global__ __launch_bounds__(256) void k_prep(
    const float* __restrict__ W1, const float* __restrict__ W2,
    const float* __restrict__ R1, const float* __restrict__ R2, const float* __restrict__ R3,
    u16* __restrict__ W1s, u16* __restrict__ W2s,
    u16* __restrict__ R1s, u16* __restrict__ R2s, u16* __restrict__ R3s) {
  int t = blockIdx.x * 256 + threadIdx.x;
  const float* src; u16* dst; int lt;
  if (t < 12288) { src = W1; dst = W1s; lt = t; }
  else {
    int u = t - 12288;
    int m = u >> 13;
    lt = u & 8191;
    if (m == 0)      { src = W2; dst = W2s; }
    else if (m == 1) { src = R1; dst = R1s; }
    else if (m == 2) { src = R2; dst = R2s; }
    else if (m == 3) { src = R3; dst = R3s; }
    else return;
  }
  int lane = lt & 63;
  int nt = (lt >> 6) & 15;
  int ks = lt >> 10;
  int col = nt * 16 + (lane & 15);
  int kb = ks * 32 + (lane >> 4) * 8;
  union { u16 u[8]; uint4 v; } o;
#pragma unroll
  for (int j = 0; j < 8; ++j) o.u[j] = f2bf(src[(size_t)(kb + j) * 256 + col]);
  *(uint4*)(dst + (size_t)lt * 8) = o.v;
}

// ---------------------------------------------------------------------------
// CSR build: histogram -> 3-stage multi-block exclusive scan -> scatter.
// ---------------------------------------------------------------------------
__global__ __launch_bounds__(256) void k_hist(const int* __restrict__ cells,
                                              int* __restrict__ counts, int E) {
  int e = blockIdx.x * 256 + threadIdx.x;
  if (e < E) atomicAdd(&counts[cells[e]], 1);
}

__global__ __launch_bounds__(256) void k_scan1(const int* __restrict__ counts,
                                               int* __restrict__ offs,
                                               int* __restrict__ bsum, int M) {
  __shared__ int ws[4];
  int tid = threadIdx.x, lane = tid & 63, wid = tid >> 6;
  int i = blockIdx.x * 256 + tid;
  int v = (i < M) ? counts[i] : 0;
  int x = v;
#pragma unroll
  for (int s = 1; s < 64; s <<= 1) { int y = __shfl_up(x, s); if (lane >= s) x += y; }
  if (lane == 63) ws[wid] = x;
  __syncthreads();
  int pre = 0;
#pragma unroll
  for (int w = 0; w < 4; ++w) if (w < wid) pre += ws[w];
  if (i < M) offs[i] = pre + x - v;
  if (tid == 255) bsum[blockIdx.x] = pre + x;
}

__global__ __launch_bounds__(256) void k_scan2(int* __restrict__ bsum, int nb) {
  __shared__ int ws[4];
  int tid = threadIdx.x, lane = tid & 63, wid = tid >> 6;
  int v = (tid < nb) ? bsum[tid] : 0;
  int x = v;
#pragma unroll
  for (int s = 1; s < 64; s <<= 1) { int y = __shfl_up(x, s); if (lane >= s) x += y; }
  if (lane == 63) ws[wid] = x;
  __syncthreads();
  int pre = 0;
#pragma unroll
  for (int w = 0; w < 4; ++w) if (w < wid) pre += ws[w];
  if (tid < nb) bsum[tid] = pre + x - v;
}

__global__ __launch_bounds__(256) void k_scan3(int* __restrict__ offs,
                                               const int* __restrict__ bsum,
                                               int* __restrict__ cursor, int M, int E) {
  int i = blockIdx.x * 256 + threadIdx.x;
  if (i < M) { int o = offs[i] + bsum[blockIdx.x]; offs[i] = o; cursor[i] = o; }
  if (i == M) offs[M] = E;
}

__global__ __launch_bounds__(256) void k_scatter(const int* __restrict__ cells,
                                                 const int* __restrict__ nodes,
                                                 int* __restrict__ cursor,
                                                 int* __restrict__ sorted, int E) {
  int e = blockIdx.x * 256 + threadIdx.x;
  if (e < E) {
    int c = cells[e];
    int p = atomicAdd(&cursor[c], 1);
    sorted[p] = nodes[e];
  }
}

// ---------------------------------------------------------------------------
// k_phi: H = relu(relu(X@W1+b1)@W2+b2), col-split, single 32KB LDS buffer.
// Block = 4 waves x 64 rows; wave w owns cols [w*64, w*64+64).
// A-tile / h1 / h2 time-share buf[64][256] bf16 (XOR swizzle ^((row&15)<<3),
// u16 units). B-fragments loaded in-loop (compiler hoists next-iter loads);
// VGPR budget kept ~104 (<=128 -> 16 waves/CU; LDS 32KB -> 4-5 blocks/CU).
// ---------------------------------------------------------------------------
__global__ __launch_bounds__(256, 2) void k_phi(
    const float* __restrict__ X,
    const u16* __restrict__ W1s, const float* __restrict__ b1,
    const u16* __restrict__ W2s, const float* __restrict__ b2,
    u16* __restrict__ H, int N) {
  __shared__ __align__(16) u16 buf[64 * 256];
  const int tid = threadIdx.x, lane = tid & 63, wid = tid >> 6;
  const int g = lane >> 4, r16 = lane & 15;
  const int rbase = blockIdx.x * 64;

  const u16* w1p = W1s + (size_t)(wid * 4) * 512 + lane * 8;  // + ks*8192 + n*512
  const u16* w2p = W2s + (size_t)(wid * 4) * 512 + lane * 8;

  f32x4 acc[4][4];
#pragma unroll
  for (int m = 0; m < 4; ++m)
#pragma unroll
    for (int n = 0; n < 4; ++n) acc[m][n] = (f32x4){0.f, 0.f, 0.f, 0.f};

  // ---- stage phase 0: X cols [0,256) ----
#pragma unroll
  for (int it = 0; it < 16; ++it) {
    int u = it * 256 + tid;
    int row = u >> 6, c4 = u & 63;
    int crow = rbase + row; crow = crow < N ? crow : N - 1;
    f32x4 v = *(const f32x4*)(X + (size_t)crow * 384 + c4 * 4);
    uint2 pk;
    pk.x = (unsigned int)f2bf(v[0]) | ((unsigned int)f2bf(v[1]) << 16);
    pk.y = (unsigned int)f2bf(v[2]) | ((unsigned int)f2bf(v[3]) << 16);
    *(uint2*)(buf + row * 256 + ((c4 * 4) ^ ((row & 15) << 3))) = pk;
  }
  __syncthreads();

  // ---- layer 1, K phase 0 (ks 0..7) ----
#pragma unroll
  for (int ks = 0; ks < 8; ++ks) {
    bf16x8 bfr[4];
#pragma unroll
    for (int n = 0; n < 4; ++n)
      bfr[n] = *(const bf16x8*)(w1p + (size_t)ks * 8192 + n * 512);
#pragma unroll
    for (int m = 0; m < 4; ++m) {
      int row = m * 16 + r16;
      bf16x8 af = *(const bf16x8*)(buf + row * 256 + ((ks * 32 + g * 8) ^ (r16 << 3)));
#pragma unroll
      for (int n = 0; n < 4; ++n)
        acc[m][n] = __builtin_amdgcn_mfma_f32_16x16x32_bf16(af, bfr[n], acc[m][n], 0, 0, 0);
    }
  }
  __syncthreads();  // done reading phase-0 A

  // ---- stage phase 1: X cols [256,384) into buf u16-cols [0,128) ----
#pragma unroll
  for (int it = 0; it < 8; ++it) {
    int u = it * 256 + tid;
    int row = u >> 5, c4 = u & 31;
    int crow = rbase + row; crow = crow < N ? crow : N - 1;
    f32x4 v = *(const f32x4*)(X + (size_t)crow * 384 + 256 + c4 * 4);
    uint2 pk;
    pk.x = (unsigned int)f2bf(v[0]) | ((unsigned int)f2bf(v[1]) << 16);
    pk.y = (unsigned int)f2bf(v[2]) | ((unsigned int)f2bf(v[3]) << 16);
    *(uint2*)(buf + row * 256 + ((c4 * 4) ^ ((row & 15) << 3))) = pk;
  }
  __syncthreads();

  // ---- layer 1, K phase 1 (ks 8..11) ----
#pragma unroll
  for (int ksl = 0; ksl < 4; ++ksl) {
    bf16x8 bfr[4];
#pragma unroll
    for (int n = 0; n < 4; ++n)
      bfr[n] = *(const bf16x8*)(w1p + (size_t)(8 + ksl) * 8192 + n * 512);
#pragma unroll
    for (int m = 0; m < 4; ++m) {
      int row = m * 16 + r16;
      bf16x8 af = *(const bf16x8*)(buf + row * 256 + ((ksl * 32 + g * 8) ^ (r16 << 3)));
#pragma unroll
      for (int n = 0; n < 4; ++n)
        acc[m][n] = __builtin_amdgcn_mfma_f32_16x16x32_bf16(af, bfr[n], acc[m][n], 0, 0, 0);
    }
  }
  __syncthreads();  // done reading phase-1 A; buf free for h1

  // ---- h1 = relu(acc + b1) -> buf ----
  float bias1[4];
#pragma unroll
  for (int n = 0; n < 4; ++n) bias1[n] = b1[wid * 64 + n * 16 + r16];
#pragma unroll
  for (int m = 0; m < 4; ++m)
#pragma unroll
    for (int n = 0; n < 4; ++n)
#pragma unroll
      for (int rr = 0; rr < 4; ++rr) {
        int row = m * 16 + g * 4 + rr;
        int col = wid * 64 + n * 16 + r16;
        float v = fmaxf(acc[m][n][rr] + bias1[n], 0.f);
        buf[row * 256 + (col ^ ((row & 15) << 3))] = f2bf(v);
      }
  __syncthreads();

  // ---- layer 2 ----
  f32x4 acc2[4][4];
#pragma unroll
  for (int m = 0; m < 4; ++m)
#pragma unroll
    for (int n = 0; n < 4; ++n) acc2[m][n] = (f32x4){0.f, 0.f, 0.f, 0.f};
#pragma unroll
  for (int ks = 0; ks < 8; ++ks) {
    bf16x8 bfr[4];
#pragma unroll
    for (int n = 0; n < 4; ++n)
      bfr[n] = *(const bf16x8*)(w2p + (size_t)ks * 8192 + n * 512);
#pragma unroll
    for (int m = 0; m < 4; ++m) {
      int row = m * 16 + r16;
      bf16x8 af = *(const bf16x8*)(buf + row * 256 + ((ks * 32 + g * 8) ^ (r16 << 3)));
#pragma unroll
      for (int n = 0; n < 4; ++n)
        acc2[m][n] = __builtin_amdgcn_mfma_f32_16x16x32_bf16(af, bfr[n], acc2[m][n], 0, 0, 0);
    }
  }
  __syncthreads();  // done reading h1

  // ---- h2 = relu(acc2 + b2) -> buf ----
  float bias2[4];
#pragma unroll
  for (int n = 0; n < 4; ++n) bias2[n] = b2[wid * 64 + n * 16 + r16];
#pragma unroll
  for (int m = 0; m < 4; ++m)
#pragma unroll
    for (int n = 0; n < 4; ++n)
#pragma unroll
      for (int rr = 0; rr < 4; ++rr) {
        int row = m * 16 + g * 4 + rr;
        int col = wid * 64 + n * 16 + r16;
        float v = fmaxf(acc2[m][n][rr] + bias2[n], 0.f);
        buf[row * 256 + (col ^ ((row & 15) << 3))] = f2bf(v);
      }
  __syncthreads();

  // ---- coalesced copy out ----
#pragma unroll
  for (int it = 0; it < 8; ++it) {
    int u = it * 256 + tid;
    int row = u >> 5, k8 = u & 31;
    uint4 d = *(const uint4*)(buf + row * 256 + ((k8 * 8) ^ ((row & 15) << 3)));
    int grow = rbase + row;
    if (grow < N) *(uint4*)(H + (size_t)grow * 256 + k8 * 8) = d;
  }
}

// ---------------------------------------------------------------------------
// k_cellsum: one wave per cell; pre-resolve sorted indices, __shfl-broadcast,
// 4-wide unrolled H-row loads so loads issue back-to-back.
// ---------------------------------------------------------------------------
__global__ __launch_bounds__(256) void k_cellsum(
    const u16* __restrict__ H, const int* __restrict__ sorted,
    const int* __restrict__ offs, u16* __restrict__ CS, int M) {
  const int lane = threadIdx.x & 63, wid = threadIdx.x >> 6;
  int c = blockIdx.x * 4 + wid;
  if (c >= M) return;
  int s = offs[c], e = offs[c + 1];
  float a0 = 0.f, a1 = 0.f, a2 = 0.f, a3 = 0.f;
  for (int base = s; base < e; base += 64) {
    int cnt = e - base; if (cnt > 64) cnt = 64;
    int idx = sorted[base + (lane < cnt ? lane : 0)];
    int j = 0;
    for (; j + 4 <= cnt; j += 4) {
      int n0 = __shfl(idx, j), n1 = __shfl(idx, j + 1);
      int n2 = __shfl(idx, j + 2), n3 = __shfl(idx, j + 3);
      ushort4 h0 = *(const ushort4*)(H + (size_t)n0 * 256 + lane * 4);
      ushort4 h1 = *(const ushort4*)(H + (size_t)n1 * 256 + lane * 4);
      ushort4 h2 = *(const ushort4*)(H + (size_t)n2 * 256 + lane * 4);
      ushort4 h3 = *(const ushort4*)(H + (size_t)n3 * 256 + lane * 4);
      a0 += bf2f(h0.x) + bf2f(h1.x) + bf2f(h2.x) + bf2f(h3.x);
      a1 += bf2f(h0.y) + bf2f(h1.y) + bf2f(h2.y) + bf2f(h3.y);
      a2 += bf2f(h0.z) + bf2f(h1.z) + bf2f(h2.z) + bf2f(h3.z);
      a3 += bf2f(h0.w) + bf2f(h1.w) + bf2f(h2.w) + bf2f(h3.w);
    }
    for (; j < cnt; ++j) {
      int nd = __shfl(idx, j);
      ushort4 h = *(const ushort4*)(H + (size_t)nd * 256 + lane * 4);
      a0 += bf2f(h.x); a1 += bf2f(h.y); a2 += bf2f(h.z); a3 += bf2f(h.w);
    }
  }
  ushort4 o;
  o.x = f2bf(a0); o.y = f2bf(a1); o.z = f2bf(a2); o.w = f2bf(a3);
  *(ushort4*)(CS + (size_t)c * 256 + lane * 4) = o;
}

// ---------------------------------------------------------------------------
// k_rho: OUT = relu(relu(CS@R1+c1)@R2+c2)@R3+c3, single 32KB LDS buffer,
// in-loop B-fragment loads, fp32 direct stores.
// ---------------------------------------------------------------------------
__global__ __launch_bounds__(256, 2) void k_rho(
    const u16* __restrict__ CS,
    const u16* __restrict__ R1s, const float* __restrict__ c1,
    const u16* __restrict__ R2s, const float* __restrict__ c2,
    const u16* __restrict__ R3s, const float* __restrict__ c3,
    float* __restrict__ OUT, int M) {
  __shared__ __align__(16) u16 buf[64 * 256];
  const int tid = threadIdx.x, lane = tid & 63, wid = tid >> 6;
  const int g = lane >> 4, r16 = lane & 15;
  const int rbase = blockIdx.x * 64;

  const u16* w1p = R1s + (size_t)(wid * 4) * 512 + lane * 8;
  const u16* w2p = R2s + (size_t)(wid * 4) * 512 + lane * 8;
  const u16* w3p = R3s + (size_t)(wid * 4) * 512 + lane * 8;

  // stage CS tile (already bf16)
#pragma unroll
  for (int it = 0; it < 8; ++it) {
    int u = it * 256 + tid;
    int row = u >> 5, k8 = u & 31;
    int crow = rbase + row; crow = crow < M ? crow : M - 1;
    uint4 d = *(const uint4*)(CS + (size_t)crow * 256 + k8 * 8);
    *(uint4*)(buf + row * 256 + ((k8 * 8) ^ ((row & 15) << 3))) = d;
  }
  __syncthreads();

  // ---- layer 1 ----
  f32x4 acc[4][4];
#pragma unroll
  for (int m = 0; m < 4; ++m)
#pragma unroll
    for (int n = 0; n < 4; ++n) acc[m][n] = (f32x4){0.f, 0.f, 0.f, 0.f};
#pragma unroll
  for (int ks = 0; ks < 8; ++ks) {
    bf16x8 bfr[4];
#pragma unroll
    for (int n = 0; n < 4; ++n)
      bfr[n] = *(const bf16x8*)(w1p + (size_t)ks * 8192 + n * 512);
#pragma unroll
    for (int m = 0; m < 4; ++m) {
      int row = m * 16 + r16;
      bf16x8 af = *(const bf16x8*)(buf + row * 256 + ((ks * 32 + g * 8) ^ (r16 << 3)));
#pragma unroll
      for (int n = 0; n < 4; ++n)
        acc[m][n] = __builtin_amdgcn_mfma_f32_16x16x32_bf16(af, bfr[n], acc[m][n], 0, 0, 0);
    }
  }
  __syncthreads();  // done reading CS tile

  float bias1[4];
#pragma unroll
  for (int n = 0; n < 4; ++n) bias1[n] = c1[wid * 64 + n * 16 + r16];
#pragma unroll
  for (int m = 0; m < 4; ++m)
#pragma unroll
    for (int n = 0; n < 4; ++n)
#pragma unroll
      for (int rr = 0; rr < 4; ++rr) {
        int row = m * 16 + g * 4 + rr;
        int col = wid * 64 + n * 16 + r16;
        float v = fmaxf(acc[m][n][rr] + bias1[n], 0.f);
        buf[row * 256 + (col ^ ((row & 15) << 3))] = f2bf(v);
      }
  __syncthreads();

  // ---- layer 2 ----
  f32x4 acc2[4][4];
#pragma unroll
  for (int m = 0; m < 4; ++m)
#pragma unroll
    for (int n = 0; n < 4; ++n) acc2[m][n] = (f32x4){0.f, 0.f, 0.f, 0.f};
#pragma unroll
  for (int ks = 0; ks < 8; ++ks) {
    bf16x8 bfr[4];
#pragma unroll
    for (int n = 0; n < 4; ++n)
      bfr[n] = *(const bf16x8*)(w2p + (size_t)ks * 8192 + n * 512);
#pragma unroll
    for (int m = 0; m < 4; ++m) {
      int row = m * 16 + r16;
      bf16x8 af = *(const bf16x8*)(buf + row * 256 + ((ks * 32 + g * 8) ^ (r16 << 3)));
#pragma unroll
      for (int n = 0; n < 4; ++n)
        acc2[m][n] = __builtin_amdgcn_mfma_f32_16x16x32_bf16(af, bfr[n], acc2[m][n], 0, 0, 0);
    }
  }
  __syncthreads();  // done reading h1

  float bias2[4];
#pragma unroll
  for (int n = 0; n < 4; ++n) bias2[n] = c2[wid * 64 + n * 16 + r16];
#pragma unroll
  for (int m = 0; m < 4; ++m)
#pragma unroll
    for (int n = 0; n < 4; ++n)
#pragma unroll
      for (int rr = 0; rr < 4; ++rr) {
        int row = m * 16 + g * 4 + rr;
        int col = wid * 64 + n * 16 + r16;
        float v = fmaxf(acc2[m][n][rr] + bias2[n], 0.f);
        buf[row * 256 + (col ^ ((row & 15) << 3))] = f2bf(v);
      }
  __syncthreads();

  // ---- layer 3 (no relu), direct fp32 stores ----
  f32x4 acc3[4][4];
#pragma unroll
  for (int m = 0; m < 4; ++m)
#pragma unroll
    for (int n = 0; n < 4; ++n) acc3[m][n] = (f32x4){0.f, 0.f, 0.f, 0.f};
#pragma unroll
  for (int ks = 0; ks < 8; ++ks) {
    bf16x8 bfr[4];
#pragma unroll
    for (int n = 0; n < 4; ++n)
      bfr[n] = *(const bf16x8*)(w3p + (size_t)ks * 8192 + n * 512);
#pragma unroll
    for (int m = 0; m < 4; ++m) {
      int row = m * 16 + r16;
      bf16x8 af = *(const bf16x8*)(buf + row * 256 + ((ks * 32 + g * 8) ^ (r16 << 3)));
#pragma unroll
      for (int n = 0; n < 4; ++n)
        acc3[m][n] = __builtin_amdgcn_mfma_f32_16x16x32_bf16(af, bfr[n], acc3[m][n], 0, 0, 0);
    }
  }
#pragma unroll
  for (int n = 0; n < 4; ++n) {
    float bias = c3[wid * 64 + n * 16 + r16];
#pragma unroll
    for (int m = 0; m < 4; ++m)
#pragma unroll
      for (int rr = 0; rr < 4; ++rr) {
        int grow = rbase + m * 16 + g * 4 + rr;
        if (grow < M) OUT[(size_t)grow * 256 + wid * 64 + n * 16 + r16] = acc3[m][n][rr] + bias;
      }
  }
}

// ---------------------------------------------------------------------------
extern "C" void kernel_launch(void* const* d_in, const int* in_sizes, int n_in,
                              void* d_out, int out_size, void* d_ws, size_t ws_size,
                              hipStream_t stream) {
  const float* X    = (const float*)d_in[0];
  const int* nodes  = (const int*)d_in[1];
  const int* cells  = (const int*)d_in[2];
  const float* W1   = (const float*)d_in[4];
  const float* b1   = (const float*)d_in[5];
  const float* W2   = (const float*)d_in[6];
  const float* b2   = (const float*)d_in[7];
  const float* R1   = (const float*)d_in[8];
  const float* c1   = (const float*)d_in[9];
  const float* R2   = (const float*)d_in[10];
  const float* c2   = (const float*)d_in[11];
  const float* R3   = (const float*)d_in[12];
  const float* c3   = (const float*)d_in[13];
  float* OUT = (float*)d_out;

  const int N = in_sizes[0] / 384;   // 100000
  const int E = in_sizes[1];         // 400000
  const int M = out_size / 256;      // 50000

  char* ws = (char*)d_ws;
  size_t off = 0;
  auto alloc = [&](size_t b) { size_t o = off; off += (b + 255) & ~(size_t)255; return o; };
  u16* W1s    = (u16*)(ws + alloc((size_t)12 * 16 * 64 * 8 * 2));
  u16* W2s    = (u16*)(ws + alloc((size_t)8 * 16 * 64 * 8 * 2));
  u16* R1s    = (u16*)(ws + alloc((size_t)8 * 16 * 64 * 8 * 2));
  u16* R2s    = (u16*)(ws + alloc((size_t)8 * 16 * 64 * 8 * 2));
  u16* R3s    = (u16*)(ws + alloc((size_t)8 * 16 * 64 * 8 * 2));
  u16* H      = (u16*)(ws + alloc((size_t)N * 256 * 2));
  u16* CS     = (u16*)(ws + alloc((size_t)M * 256 * 2));
  int* counts = (int*)(ws + alloc((size_t)M * 4));
  int* offs   = (int*)(ws + alloc((size_t)(M + 1) * 4));
  int* cursor = (int*)(ws + alloc((size_t)M * 4));
  int* sorted = (int*)(ws + alloc((size_t)E * 4));
  int* bsum   = (int*)(ws + alloc((size_t)256 * 4));

  const int NB = (M + 255) / 256;

  hipMemsetAsync(counts, 0, (size_t)M * 4, stream);
  k_prep<<<176, 256, 0, stream>>>(W1, W2, R1, R2, R3, W1s, W2s, R1s, R2s, R3s);
  k_hist<<<(E + 255) / 256, 256, 0, stream>>>(cells, counts, E);
  k_scan1<<<NB, 256, 0, stream>>>(counts, offs, bsum, M);
  k_scan2<<<1, 256, 0, stream>>>(bsum, NB);
  k_scan3<<<(M + 256) / 256, 256, 0, stream>>>(offs, bsum, cursor, M, E);
  k_scatter<<<(E + 255) / 256, 256, 0, stream>>>(cells, nodes, cursor, sorted, E);
  k_phi<<<(N + 63) / 64, 256, 0, stream>>>(X, W1s, b1, W2s, b2, H, N);
  k_cellsum<<<(M + 3) / 4, 256, 0, stream>>>(H, sorted, offs, CS, M);
  k_rho<<<(M + 63) / 64, 256, 0, stream>>>(CS, R1s, c1, R2s, c2, R3s, c3, OUT, M);
}